// Round 10
// baseline (535.172 us; speedup 1.0000x reference)
//
#include <hip/hip_runtime.h>
#include <stdint.h>

typedef int int32x4  __attribute__((ext_vector_type(4)));
typedef int int32x16 __attribute__((ext_vector_type(16)));

#define IN_F   4096
#define OUT_F  4096
#define ROWS   8192   /* 4 * 2048 */

#define BM 256
#define BN 128
#define BK 128

// async global->LDS, 16B per lane; LDS side must be lane-contiguous (m104/m108)
#define GLOAD_LDS16(g, l)                                                      \
  __builtin_amdgcn_global_load_lds(                                            \
      (const __attribute__((address_space(1))) void*)(g),                      \
      (__attribute__((address_space(3))) void*)(l), 16, 0, 0)

__device__ __forceinline__ int pack4i(int a, int b, int c, int d) {
  return (a & 0xff) | ((b & 0xff) << 8) | ((c & 0xff) << 16) | (d << 24);
}

// ---- fused conversion: x int32->int8 and w fp32->int8, one launch -----------
#define XB 32768
#define WB 16384
__global__ void __launch_bounds__(256) cvt_kernel(const int4* __restrict__ x,
                                                  const float4* __restrict__ w,
                                                  int* __restrict__ ox,
                                                  int* __restrict__ ow) {
  int b = blockIdx.x;
  if (b < XB) {
    size_t i = (size_t)b * 256 + threadIdx.x;
    int4 a = x[i];
    ox[i] = pack4i(a.x, a.y, a.z, a.w);
  } else {
    size_t i = (size_t)(b - XB) * 256 + threadIdx.x;
    float4 a = w[i];
    ow[i] = pack4i(__float2int_rn(a.x), __float2int_rn(a.y),
                   __float2int_rn(a.z), __float2int_rn(a.w));
  }
}

// ---- i8 MFMA GEMM: C[m,n] = sum_k A[m,k]*B[n,k]  (both row-major [rows][K]) -
// R9 post-mortem: MfmaUtil pinned ~40% across every LDS-side variant -> waves
// stall on the LDS round-trip latency (lgkmcnt), phase-locked by the barrier.
// NEW STRUCTURE: A operand loaded DIRECTLY global->VGPR (lane addresses are
// MFMA-fragment-ready; each 64B line consumed 4x across ks -> L1-served;
// waits are deep-batched vmcnt, no barrier coupling).  Only B goes through
// LDS (16 KB single buffer).  A-loads for the whole iter issue before the
// barrier, overlapping B staging.
// Block 256x128, BK=128; 4 waves 2x2, wave tile 128x64 = 4x2
// mfma_i32_32x32x32_i8.  A-operand: m = lane&31, k = (lane>>5)*16 + j.
// C/D: col = lane&31, row = (reg&3)+8*(reg>>2)+4*(lane>>5) [m74/m101].
// B LDS XOR-swizzle (on GLOBAL src addr during staging): chunk (row,kc) at
// slot kc ^ (row&7).
__global__ void __launch_bounds__(256, 2) gemm_i8_kernel(
    const int8_t* __restrict__ A8, const int8_t* __restrict__ B8,
    const float* __restrict__ bias, const float* __restrict__ alpha_p,
    int* __restrict__ out) {
  __shared__ int8_t Bs[BN * BK];  // 16 KB

  const int t = threadIdx.x;
  const int wave = t >> 6;
  const int lane = t & 63;
  const int l31 = lane & 31;
  const int hi  = lane >> 5;    // 0..1
  const int wm = wave >> 1;     // 0..1  row half (128 rows)
  const int wn = wave & 1;      // 0..1  col half (64 cols)

  const int bn = blockIdx.x;    // 0..31
  const int bm = blockIdx.y;    // 0..31

  // B staging: 1024 chunks of 16B; thread t owns chunks t+256j, j=0..3.
  const int rowS = t >> 3;                          // 0..31
  const int colS = ((t & 7) ^ (rowS & 7)) * 16;
  const int8_t* bg = B8 + (size_t)(bn * BN + rowS) * IN_F + colS;

  // A direct: lane's fragment base (row = bm*256 + wm*128 + l31, col = hi*16)
  const int8_t* ap = A8 + (size_t)(bm * BM + wm * 128 + l31) * IN_F + hi * 16;

  // B fragment read idx (16B units): row*8 + (kc ^ (row&7)), kc = ks*2+hi.
  const int swz = l31 & 7;
  const int brow0 = (wn * 64 + l31) * 8;   // +ni*256

  int32x16 acc[4][2] = {};

  for (int k0 = 0; k0 < IN_F; k0 += BK) {
    // stage B tile (async to LDS)
#pragma unroll
    for (int j = 0; j < 4; ++j)
      GLOAD_LDS16(bg + k0 + (size_t)(32 * j) * IN_F, Bs + t * 16 + 4096 * j);

    // A fragments for the whole iter, straight to VGPRs (64 regs);
    // issued before the barrier so latency overlaps B staging + drain.
    int32x4 af[4][4];
#pragma unroll
    for (int ks = 0; ks < 4; ++ks)
#pragma unroll
      for (int mi = 0; mi < 4; ++mi)
        af[ks][mi] = *(const int32x4*)(ap + (size_t)(mi * 32) * IN_F + k0 + ks * 32);

    __syncthreads();

    const int32x4* Bs4 = (const int32x4*)Bs;
#pragma unroll
    for (int ks = 0; ks < 4; ++ks) {
      const int ksw = (ks * 2 + hi) ^ swz;
      int32x4 bf[2];
#pragma unroll
      for (int i = 0; i < 2; ++i) bf[i] = Bs4[brow0 + i * 256 + ksw];
#pragma unroll
      for (int mi = 0; mi < 4; ++mi)
#pragma unroll
        for (int ni = 0; ni < 2; ++ni)
          acc[mi][ni] = __builtin_amdgcn_mfma_i32_32x32x32_i8(
              af[ks][mi], bf[ni], acc[mi][ni], 0, 0, 0);
    }
    __syncthreads();  // protect Bs against next-iter overwrite
  }

  // epilogue: C/D col = lane&31, row = (reg&3) + 8*(reg>>2) + 4*hi
  const float alpha = *alpha_p;
#pragma unroll
  for (int mi = 0; mi < 4; ++mi) {
    const int rowt = bm * BM + wm * 128 + mi * 32 + hi * 4;
#pragma unroll
    for (int ni = 0; ni < 2; ++ni) {
      const int col = bn * BN + wn * 64 + ni * 32 + l31;
      const float bv = bias[col];
#pragma unroll
      for (int r = 0; r < 16; ++r) {
        const int row = rowt + (r & 3) + 8 * (r >> 2);
        float v = rintf((float)acc[mi][ni][r] * alpha + bv);
        v = fminf(fmaxf(v, -128.f), 127.f);
        out[(size_t)row * OUT_F + col] = (int)v;
      }
    }
  }
}

extern "C" void kernel_launch(void* const* d_in, const int* in_sizes, int n_in,
                              void* d_out, int out_size, void* d_ws, size_t ws_size,
                              hipStream_t stream) {
  const int*   x     = (const int*)d_in[0];    // [8192, 4096] int8-valued
  const float* w     = (const float*)d_in[1];  // [4096, 4096] int8-valued
  const float* bias  = (const float*)d_in[2];  // [4096]
  const float* alpha = (const float*)d_in[3];  // scalar
  int* out = (int*)d_out;                      // [8192, 4096] int32 (int8 values)

  int8_t* x8 = (int8_t*)d_ws;                        // 33,554,432 B
  int8_t* w8 = x8 + (size_t)ROWS * IN_F;             // 16,777,216 B (total 48 MB)

  cvt_kernel<<<XB + WB, 256, 0, stream>>>((const int4*)x, (const float4*)w,
                                          (int*)x8, (int*)w8);

  dim3 grid(OUT_F / BN, ROWS / BM);  // (32, 32)
  gemm_i8_kernel<<<grid, 256, 0, stream>>>(x8, w8, bias, alpha, out);
}

// Round 11
// 520.174 us; speedup vs baseline: 1.0288x; 1.0288x over previous
//
#include <hip/hip_runtime.h>
#include <stdint.h>

typedef int int32x4  __attribute__((ext_vector_type(4)));
typedef int int32x16 __attribute__((ext_vector_type(16)));

#define IN_F   4096
#define OUT_F  4096
#define ROWS   8192   /* 4 * 2048 */

#define KB_N   128    /* k-blocks of 32 */

__device__ __forceinline__ int pack4i(int a, int b, int c, int d) {
  return (a & 0xff) | ((b & 0xff) << 8) | ((c & 0xff) << 16) | (d << 24);
}

// ---- conversion to FRAGMENT-MAJOR int8 blobs --------------------------------
// Blob = 1 KB = one 32(m/n) x 32(k) tile in mfma_i32_32x32x32_i8 A/B-operand
// order: byte lane*16+j  <->  element (row = lane&31, k = (lane>>5)*16 + j).
// Blob id = row_blk * 128 + k_blk  (k fastest -> GEMM streams consecutive KB).
// One thread per 16 output bytes: reads 64 B contiguous (4x16B, fully
// consumed), writes 16 B at g*16 (perfectly coalesced).
// blocks [0, XB): x (int32 in);  [XB, XB+WB): w (fp32 in).
#define XB 8192
#define WB 4096
__global__ void __launch_bounds__(256) cvt_kernel(const int* __restrict__ x,
                                                  const float* __restrict__ w,
                                                  int4* __restrict__ ox,
                                                  int4* __restrict__ ow) {
  const int b = blockIdx.x;
  if (b < XB) {
    const size_t g = (size_t)b * 256 + threadIdx.x;
    const int blob = (int)(g >> 6);
    const int lane = (int)(g & 63);
    const int m = (blob >> 7) * 32 + (lane & 31);
    const int k = (blob & 127) * 32 + (lane >> 5) * 16;
    const int4* xp = (const int4*)(x + (size_t)m * IN_F + k);
    int4 a = xp[0], c = xp[1], d = xp[2], e = xp[3];
    int4 r;
    r.x = pack4i(a.x, a.y, a.z, a.w);
    r.y = pack4i(c.x, c.y, c.z, c.w);
    r.z = pack4i(d.x, d.y, d.z, d.w);
    r.w = pack4i(e.x, e.y, e.z, e.w);
    ox[g] = r;
  } else {
    const size_t g = (size_t)(b - XB) * 256 + threadIdx.x;
    const int blob = (int)(g >> 6);
    const int lane = (int)(g & 63);
    const int n = (blob >> 7) * 32 + (lane & 31);
    const int k = (blob & 127) * 32 + (lane >> 5) * 16;
    const float4* wp = (const float4*)(w + (size_t)n * IN_F + k);
    float4 a = wp[0], c = wp[1], d = wp[2], e = wp[3];
    int4 r;
    r.x = pack4i(__float2int_rn(a.x), __float2int_rn(a.y), __float2int_rn(a.z), __float2int_rn(a.w));
    r.y = pack4i(__float2int_rn(c.x), __float2int_rn(c.y), __float2int_rn(c.z), __float2int_rn(c.w));
    r.z = pack4i(__float2int_rn(d.x), __float2int_rn(d.y), __float2int_rn(d.z), __float2int_rn(d.w));
    r.w = pack4i(__float2int_rn(e.x), __float2int_rn(e.y), __float2int_rn(e.z), __float2int_rn(e.w));
    ow[g] = r;
  }
}

// ---- i8 MFMA GEMM, NO LDS / NO BARRIERS -------------------------------------
// R10 lesson: direct global operands need CONTIGUOUS per-wave loads.  With
// fragment-major blobs, each fragment is one coalesced 1 KB global_load_
// dwordx4 (lane*16).  No __syncthreads anywhere -> no vmcnt(0) drain, no
// phase-lock; loads pipeline 2-deep in registers, waves free-run, operands
// served from L1/L2 (w8 16.7 MB, x8 33.5 MB: L2/L3-resident).
// Block 256x128 out (grid 32x32); 4 waves 2x2, wave tile 128x64 = 4x2
// mfma_i32_32x32x32_i8 (acc 128 VGPR).
// C/D: col = lane&31, row = (reg&3)+8*(reg>>2)+4*(lane>>5) [m74/m101].
__global__ void __launch_bounds__(256, 2) gemm_i8_kernel(
    const int8_t* __restrict__ A8, const int8_t* __restrict__ B8,
    const float* __restrict__ bias, const float* __restrict__ alpha_p,
    int* __restrict__ out) {
  const int t = threadIdx.x;
  const int wave = t >> 6;
  const int lane = t & 63;
  const int l31 = lane & 31;
  const int hi  = lane >> 5;    // 0..1
  const int wm = wave >> 1;     // 0..1  row half (128 rows = 4 m-blks)
  const int wn = wave & 1;      // 0..1  col half (64 cols = 2 n-blks)

  const int bn = blockIdx.x;    // 0..31
  const int bm = blockIdx.y;    // 0..31

  // blob bases: A blob (m_blk, kb) at (m_blk*128 + kb)*1024; lane offset *16.
  const int8_t* Ab = A8 + ((size_t)(bm * 8 + wm * 4) * KB_N) * 1024 + lane * 16;
  const int8_t* Bb = B8 + ((size_t)(bn * 4 + wn * 2) * KB_N) * 1024 + lane * 16;

  int32x16 acc[4][2] = {};
  int32x4 a[2][4], bf[2][2];

#define LOADK(s, kb)                                                           \
  do {                                                                         \
    _Pragma("unroll")                                                          \
    for (int mi = 0; mi < 4; ++mi)                                             \
      a[s][mi] = *(const int32x4*)(Ab + ((size_t)mi * KB_N + (kb)) * 1024);    \
    _Pragma("unroll")                                                          \
    for (int ni = 0; ni < 2; ++ni)                                             \
      bf[s][ni] = *(const int32x4*)(Bb + ((size_t)ni * KB_N + (kb)) * 1024);   \
  } while (0)

#define MFMA8(s)                                                               \
  do {                                                                         \
    _Pragma("unroll")                                                          \
    for (int mi = 0; mi < 4; ++mi)                                             \
      _Pragma("unroll")                                                        \
      for (int ni = 0; ni < 2; ++ni)                                           \
        acc[mi][ni] = __builtin_amdgcn_mfma_i32_32x32x32_i8(                   \
            a[s][mi], bf[s][ni], acc[mi][ni], 0, 0, 0);                        \
  } while (0)

  LOADK(0, 0);
  for (int kb = 0; kb < KB_N - 2; kb += 2) {
    LOADK(1, kb + 1);
    MFMA8(0);
    LOADK(0, kb + 2);
    MFMA8(1);
  }
  // tail: set0 holds kb=126
  LOADK(1, KB_N - 1);
  MFMA8(0);
  MFMA8(1);
#undef LOADK
#undef MFMA8

  // epilogue: C/D col = lane&31, row = (reg&3) + 8*(reg>>2) + 4*hi
  const float alpha = *alpha_p;
#pragma unroll
  for (int mi = 0; mi < 4; ++mi) {
    const int rowt = bm * 256 + wm * 128 + mi * 32 + hi * 4;
#pragma unroll
    for (int ni = 0; ni < 2; ++ni) {
      const int col = bn * 128 + wn * 64 + ni * 32 + l31;
      const float bv = bias[col];
#pragma unroll
      for (int r = 0; r < 16; ++r) {
        const int row = rowt + (r & 3) + 8 * (r >> 2);
        float v = rintf((float)acc[mi][ni][r] * alpha + bv);
        v = fminf(fmaxf(v, -128.f), 127.f);
        out[(size_t)row * OUT_F + col] = (int)v;
      }
    }
  }
}

extern "C" void kernel_launch(void* const* d_in, const int* in_sizes, int n_in,
                              void* d_out, int out_size, void* d_ws, size_t ws_size,
                              hipStream_t stream) {
  const int*   x     = (const int*)d_in[0];    // [8192, 4096] int8-valued
  const float* w     = (const float*)d_in[1];  // [4096, 4096] int8-valued
  const float* bias  = (const float*)d_in[2];  // [4096]
  const float* alpha = (const float*)d_in[3];  // scalar
  int* out = (int*)d_out;                      // [8192, 4096] int32 (int8 values)

  int8_t* x8 = (int8_t*)d_ws;                        // 33,554,432 B, fragment-major
  int8_t* w8 = x8 + (size_t)ROWS * IN_F;             // 16,777,216 B, fragment-major

  cvt_kernel<<<XB + WB, 256, 0, stream>>>(x, w, (int4*)x8, (int4*)w8);

  dim3 grid(OUT_F / 128, ROWS / 256);  // (32, 32)
  gemm_i8_kernel<<<grid, 256, 0, stream>>>(x8, w8, bias, alpha, out);
}